// Round 7
// baseline (185.067 us; speedup 1.0000x reference)
//
#include <hip/hip_runtime.h>
#include <hip/hip_bf16.h>

// ---- types ----
typedef __bf16 bf16_t;
typedef __bf16 bf16x8 __attribute__((ext_vector_type(8)));
typedef __bf16 bf16x4 __attribute__((ext_vector_type(4)));
typedef float  f32x4  __attribute__((ext_vector_type(4)));

#define NROWS 8192
#define INDIM 256
#define HID   256
#define NCAT  512

// async global->LDS, 16B per lane (dest = wave-uniform base + lane*16)
__device__ __forceinline__ void gload16(const bf16_t* g, bf16_t* l) {
    __builtin_amdgcn_global_load_lds(
        (const __attribute__((address_space(1))) void*)g,
        (__attribute__((address_space(3))) void*)l,
        16, 0, 0);
}

// raw barrier (no implicit cnt drain)
__device__ __forceinline__ void bar() {
    asm volatile("" ::: "memory");
    __builtin_amdgcn_s_barrier();
    asm volatile("" ::: "memory");
}

#define VMCNT8 asm volatile("s_waitcnt vmcnt(8)" ::: "memory")
#define VMCNT0 asm volatile("s_waitcnt vmcnt(0)" ::: "memory")
#define LGKM0  asm volatile("s_waitcnt lgkmcnt(0)" ::: "memory")

// ============ kernel 1: row sums (read-only) + weight transposes ============
__global__ __launch_bounds__(256) void k_rowsum(const float* __restrict__ adj,
                                                float* __restrict__ d_inv,
                                                const float* __restrict__ Wf,
                                                const float* __restrict__ Ws,
                                                bf16_t* __restrict__ Wtf,
                                                bf16_t* __restrict__ Wts) {
    const int b = blockIdx.x;
    if (b >= NROWS / 4) {
        const int i = (b - NROWS / 4) * 256 + threadIdx.x;
        const int n = i >> 8, k = i & 255;
        Wtf[i] = (bf16_t)Wf[k * 256 + n];
        Wts[i] = (bf16_t)Ws[k * 256 + n];
        return;
    }
    const int lane = threadIdx.x & 63;
    const int wid  = threadIdx.x >> 6;
    const int row  = b * 4 + wid;
    const float4* rp = (const float4*)(adj + (size_t)row * NROWS);
    float s = 0.f;
#pragma unroll 8
    for (int i = lane; i < NROWS / 4; i += 64) {
        float4 v = rp[i];
        s += (v.x + v.y) + (v.z + v.w);
    }
#pragma unroll
    for (int off = 32; off; off >>= 1) s += __shfl_down(s, off);
    if (lane == 0) d_inv[row] = 1.0f / sqrtf(s + 1e-9f);
}

// ===================== kernel 2: Yt[c][j] = bf16(d_j * X[j][c]) ==============
__global__ __launch_bounds__(256) void k_prep_x(const float* __restrict__ fx,
                                                const float* __restrict__ sx,
                                                const float* __restrict__ d_inv,
                                                bf16_t* __restrict__ Yt) {
    __shared__ bf16_t T[64][72];
    const int tid = threadIdx.x;
    const int j0 = blockIdx.x * 64;
    const int c0 = blockIdx.y * 64;
    const float* src = (c0 < 256) ? fx : sx;
    const int cc0 = (c0 < 256) ? c0 : (c0 - 256);
#pragma unroll
    for (int i = 0; i < 4; ++i) {
        int s = tid + i * 256;
        int jr = s >> 4, c4 = (s & 15) * 4;
        float dj = d_inv[j0 + jr];
        float4 v = *(const float4*)(src + (size_t)(j0 + jr) * 256 + cc0 + c4);
        bf16x4 o;
        o[0] = (bf16_t)(v.x * dj); o[1] = (bf16_t)(v.y * dj);
        o[2] = (bf16_t)(v.z * dj); o[3] = (bf16_t)(v.w * dj);
        *(bf16x4*)(&T[jr][c4]) = o;
    }
    __syncthreads();
#pragma unroll
    for (int i = 0; i < 4; ++i) {
        int s = tid + i * 256;
        int cr = s >> 4, j4 = (s & 15) * 4;
        bf16x4 o;
        o[0] = T[j4 + 0][cr]; o[1] = T[j4 + 1][cr];
        o[2] = T[j4 + 2][cr]; o[3] = T[j4 + 3][cr];
        *(bf16x4*)(Yt + (size_t)(c0 + cr) * NROWS + j0 + j4) = o;
    }
}

// ========= kernel 3: 128x128 GEMM, 2 blocks/CU (cross-block overlap) =======
// Rounds 2-6 showed the 256^2 one-block-per-CU structure is insensitive to
// in-block schedule permutations (+-2us): the 8-wave single barrier domain
// serializes on every latency bubble with nothing else on the CU to issue.
// This round: 128^2 tiles, 256 threads (2x2 waves), BK=64, LDS 64KB (A,B
// double-buffered) -> TWO independent blocks per CU; when one block stalls
// on its end-of-iter DMA drain, the other block's waves issue (m97's
// mechanism).  Grid 1024 = 64y x 4x x 4z, z pinned per XCD pair.
// Per-iter FIFO (per wave): D(t+1) DMA -> a_write(As[nxt]<-R) [compiler
// vmcnt(4) waits L(t+1), issued last iter] -> L(t+2)->R -> frag reads(cur)
// -> 32 MFMA -> VMCNT(8) [drains D(t+1), keeps L(t+2)] -> bar.
// Cross-wave safety: every slot's write/DMA is drain-certified (counted
// vmcnt / in-order lgkm before MFMA) >= 1 barrier before any wave reads it;
// every read is certified (pre-MFMA lgkm) >= 1 barrier before the slot's
// overwrite issues.  Tail: VMCNT0 at t==NT-2; no staging at t==NT-1.

__device__ __forceinline__ void stage_b128(bf16_t* dst, const bf16_t* gsrc,
                                           int tid) {
#pragma unroll
    for (int cc = 0; cc < 4; ++cc) {
        int r    = cc * 32 + (tid >> 3);
        int gcol = ((tid & 7) * 8) ^ ((r & 7) * 8);   // involution
        gload16(gsrc + (size_t)r * NROWS + gcol, dst + cc * 2048 + tid * 8);
    }
}

// fp32 A tile (128 rows x 64 cols): 32 f32/thread -> R[8]
__device__ __forceinline__ void a_load128(const float* Ag, size_t k, int tid,
                                          f32x4 R[8]) {
#pragma unroll
    for (int cc = 0; cc < 4; ++cc) {
        const float* p = Ag + (size_t)(cc * 32 + (tid >> 3)) * NROWS
                            + k + (tid & 7) * 8;
        R[cc * 2 + 0] = *(const f32x4*)(p);
        R[cc * 2 + 1] = *(const f32x4*)(p + 4);
    }
}

// cvt + write with the same XOR swizzle the read path uses (write-side)
__device__ __forceinline__ void a_write128(bf16_t* dst, const f32x4 R[8],
                                           int tid) {
#pragma unroll
    for (int cc = 0; cc < 4; ++cc) {
        int r   = cc * 32 + (tid >> 3);
        int col = ((tid & 7) * 8) ^ ((r & 7) * 8);
        f32x4 v0 = R[cc * 2], v1 = R[cc * 2 + 1];
        bf16x8 o;
        o[0] = (bf16_t)v0[0]; o[1] = (bf16_t)v0[1];
        o[2] = (bf16_t)v0[2]; o[3] = (bf16_t)v0[3];
        o[4] = (bf16_t)v1[0]; o[5] = (bf16_t)v1[1];
        o[6] = (bf16_t)v1[2]; o[7] = (bf16_t)v1[3];
        *(bf16x8*)(dst + r * 64 + col) = o;
    }
}

__device__ __forceinline__ void frag_ld4(const bf16_t* base, bf16x8 f[4][2],
                                         int row0, int c0, int c1) {
#pragma unroll
    for (int i = 0; i < 4; ++i) {
        f[i][0] = *(const bf16x8*)(base + (row0 + i * 16) * 64 + c0);
        f[i][1] = *(const bf16x8*)(base + (row0 + i * 16) * 64 + c1);
    }
}

__global__ __launch_bounds__(256, 2) void k_gemm7(const float* __restrict__ adj,
                                                  const bf16_t* __restrict__ Yt,
                                                  bf16_t* __restrict__ msgp,
                                                  int KCH) {
    __shared__ bf16_t SH[4 * 8192];              // 64 KB: As0,As1,Bs0,Bs1
    bf16_t* As = SH;
    bf16_t* Bs = SH + 2 * 8192;
    const int tid  = threadIdx.x;
    const int lane = tid & 63;
    const int w    = tid >> 6;                   // 0..3
    const int wrow = w >> 1, wcol = w & 1;       // 2M x 2N waves
    const int lr = lane & 15, hi = lane >> 4;

    // z-per-XCD-pair decode; within XCD, consecutive j share the A panel
    const int bid = blockIdx.x;                  // 0..1023
    const int cx = bid & 7;                      // XCD
    const int j  = bid >> 3;                     // 0..127
    const int z  = cx >> 1;                      // K-chunk
    const int x  = j & 3;                        // N-tile (shares A panel)
    const int y  = (cx & 1) * 32 + (j >> 2);     // M-tile 0..63
    const int m0 = y * 128, n0 = x * 128;
    const size_t kbase = (size_t)z * KCH;

    const float*  Ag = adj + (size_t)m0 * NROWS + kbase;
    const bf16_t* Bg = Yt + (size_t)n0 * NROWS + kbase;

    const int sw = (lr & 7) * 8;                 // read-side swizzle
    const int c0 = (hi * 8) ^ sw;
    const int c1 = c0 ^ 32;
    const int arow = wrow * 64 + lr;
    const int brow = wcol * 64 + lr;

    f32x4 acc[4][4] = {};
    const int NT = KCH / 64;

    f32x4 R[8];                                  // A staging (32 VGPR)

    // prologue: tile0 A+B staged; R <- tile1 A
    {
        f32x4 T[8];
        stage_b128(Bs + 0, Bg, tid);             // D(0)
        a_load128(Ag, 0, tid, T);                // Lp(0)
        a_write128(As + 0, T, tid);              // vmcnt wait drains D(0),Lp(0)
        a_load128(Ag, 64, tid, R);               // L(1), stays in flight
        LGKM0;                                   // own ds_writes published
    }
    bar();

    for (int t = 0; t < NT; ++t) {
        const int cur = t & 1, nxt = cur ^ 1;
        bf16_t* Ac = As + cur * 8192;
        bf16_t* An = As + nxt * 8192;
        bf16_t* Bc = Bs + cur * 8192;
        bf16_t* Bn = Bs + nxt * 8192;
        if (t + 1 < NT) {
            stage_b128(Bn, Bg + (size_t)(t + 1) * 64, tid);   // D(t+1)
            a_write128(An, R, tid);       // compiler vmcnt(4): waits L(t+1)
        }
        if (t + 2 < NT)
            a_load128(Ag, (size_t)(t + 2) * 64, tid, R);      // L(t+2)

        bf16x8 af[4][2], bf[4][2];
        frag_ld4(Ac, af, arow, c0, c1);
        frag_ld4(Bc, bf, brow, c0, c1);

        __builtin_amdgcn_s_setprio(1);
#pragma unroll
        for (int ks = 0; ks < 2; ++ks)
#pragma unroll
            for (int mi = 0; mi < 4; ++mi)
#pragma unroll
                for (int ni = 0; ni < 4; ++ni)
                    acc[mi][ni] = __builtin_amdgcn_mfma_f32_16x16x32_bf16(
                        af[mi][ks], bf[ni][ks], acc[mi][ni], 0, 0, 0);
        __builtin_amdgcn_s_setprio(0);

        if (t + 2 < NT) { VMCNT8; }     // drain D(t+1); keep L(t+2) in flight
        else if (t + 1 < NT) { VMCNT0; }             // t == NT-2: drain last D
        bar();
    }

    // epilogue: two 64-row LDS-transpose passes (f32, stride 129 = 33KB)
    bf16_t* mpb = msgp + (size_t)z * NROWS * NCAT;
    float* ep = (float*)SH;
#pragma unroll
    for (int p = 0; p < 2; ++p) {
        bar();
#pragma unroll
        for (int mi = 0; mi < 2; ++mi)
#pragma unroll
            for (int ni = 0; ni < 4; ++ni)
#pragma unroll
                for (int r = 0; r < 4; ++r)
                    ep[(wrow * 32 + mi * 16 + hi * 4 + r) * 129
                       + wcol * 64 + ni * 16 + lr] = acc[p * 2 + mi][ni][r];
        LGKM0;
        bar();
        const int q = tid >> 2, cb = (tid & 3) * 32;
        const int gr = m0 + (q >> 5) * 64 + p * 32 + (q & 31);
        bf16_t* gp = mpb + (size_t)gr * NCAT + n0 + cb;
#pragma unroll
        for (int j2 = 0; j2 < 4; ++j2) {
            f32x4 v0 = *(const f32x4*)(ep + q * 129 + cb + j2 * 8);
            f32x4 v1 = *(const f32x4*)(ep + q * 129 + cb + j2 * 8 + 4);
            bf16x8 o;
            o[0] = (bf16_t)v0[0]; o[1] = (bf16_t)v0[1];
            o[2] = (bf16_t)v0[2]; o[3] = (bf16_t)v0[3];
            o[4] = (bf16_t)v1[0]; o[5] = (bf16_t)v1[1];
            o[6] = (bf16_t)v1[2]; o[7] = (bf16_t)v1[3];
            *(bf16x8*)(gp + j2 * 8) = o;
        }
    }
}

// ===================== kernel 4: H_f/H_s + attention + blend =================
template <int NP>
__global__ __launch_bounds__(256) void k_fuse(const bf16_t* __restrict__ msg,
                                              const float* __restrict__ d_inv,
                                              const bf16_t* __restrict__ Wtf,
                                              const bf16_t* __restrict__ Wts,
                                              const float* __restrict__ bfv,
                                              const float* __restrict__ bsv,
                                              const float* __restrict__ Watt,
                                              const float* __restrict__ batt,
                                              float* __restrict__ out) {
    __shared__ bf16_t Ms[32][520];
    __shared__ float attnbuf[4][32];
    const int tid = threadIdx.x, lane = tid & 63, w = tid >> 6;
    const int r0 = blockIdx.x * 32;
    const int lr = lane & 15, lk = (lane >> 4) * 8;

#pragma unroll
    for (int i = 0; i < 8; ++i) {
        int s = tid + i * 256;              // 0..2047
        int r = s >> 6, c8 = (s & 63) * 8;
        float di = d_inv[r0 + r];
        size_t off = (size_t)(r0 + r) * NCAT + c8;
        float a8[8] = {};
#pragma unroll
        for (int p = 0; p < NP; ++p) {
            bf16x8 v = *(const bf16x8*)(msg + (size_t)p * NROWS * NCAT + off);
#pragma unroll
            for (int j = 0; j < 8; ++j) a8[j] += (float)v[j];
        }
        bf16x8 o;
#pragma unroll
        for (int j = 0; j < 8; ++j) o[j] = (bf16_t)(a8[j] * di);
        *(bf16x8*)(&Ms[r][c8]) = o;
    }
    __syncthreads();

    f32x4 accf[2][4] = {}, accs[2][4] = {};
#pragma unroll
    for (int ks = 0; ks < 8; ++ks) {
        bf16x8 af[2], as2[2];
#pragma unroll
        for (int mi = 0; mi < 2; ++mi) {
            af[mi]  = *(const bf16x8*)(&Ms[mi * 16 + lr][ks * 32 + lk]);
            as2[mi] = *(const bf16x8*)(&Ms[mi * 16 + lr][256 + ks * 32 + lk]);
        }
#pragma unroll
        for (int ni = 0; ni < 4; ++ni) {
            int col = w * 64 + ni * 16 + lr;
            bf16x8 bwf = *(const bf16x8*)(Wtf + col * 256 + ks * 32 + lk);
            bf16x8 bws = *(const bf16x8*)(Wts + col * 256 + ks * 32 + lk);
#pragma unroll
            for (int mi = 0; mi < 2; ++mi) {
                accf[mi][ni] = __builtin_amdgcn_mfma_f32_16x16x32_bf16(
                    af[mi], bwf, accf[mi][ni], 0, 0, 0);
                accs[mi][ni] = __builtin_amdgcn_mfma_f32_16x16x32_bf16(
                    as2[mi], bws, accs[mi][ni], 0, 0, 0);
            }
        }
    }

    float par[2][4] = {};
#pragma unroll
    for (int ni = 0; ni < 4; ++ni) {
        int col = w * 64 + ni * 16 + lr;
        float bf_ = bfv[col], bs_ = bsv[col];
        float wf = Watt[col], ws_ = Watt[256 + col];
#pragma unroll
        for (int mi = 0; mi < 2; ++mi)
#pragma unroll
            for (int r = 0; r < 4; ++r) {
                float f = accf[mi][ni][r] + bf_; f = f > 0.f ? f : 0.f;
                float s = accs[mi][ni][r] + bs_; s = s > 0.f ? s : 0.f;
                accf[mi][ni][r] = f; accs[mi][ni][r] = s;
                par[mi][r] += f * wf + s * ws_;
            }
    }
#pragma unroll
    for (int off = 1; off < 16; off <<= 1)
#pragma unroll
        for (int mi = 0; mi < 2; ++mi)
#pragma unroll
            for (int r = 0; r < 4; ++r)
                par[mi][r] += __shfl_xor(par[mi][r], off);
    if (lr == 0) {
#pragma unroll
        for (int mi = 0; mi < 2; ++mi)
#pragma unroll
            for (int r = 0; r < 4; ++r)
                attnbuf[w][mi * 16 + (lane >> 4) * 4 + r] = par[mi][r];
    }
    __syncthreads();

    const float ba = batt[0];
#pragma unroll
    for (int mi = 0; mi < 2; ++mi)
#pragma unroll
        for (int r = 0; r < 4; ++r) {
            int rr = mi * 16 + (lane >> 4) * 4 + r;
            float tot = attnbuf[0][rr] + attnbuf[1][rr] + attnbuf[2][rr] +
                        attnbuf[3][rr] + ba;
            float attn = 1.0f / (1.0f + expf(-tot));
#pragma unroll
            for (int ni = 0; ni < 4; ++ni) {
                int col = w * 64 + ni * 16 + lr;
                out[(size_t)(r0 + rr) * 256 + col] =
                    attn * accf[mi][ni][r] + (1.0f - attn) * accs[mi][ni][r];
            }
        }
}

// ===================== launch =====================
extern "C" void kernel_launch(void* const* d_in, const int* in_sizes, int n_in,
                              void* d_out, int out_size, void* d_ws, size_t ws_size,
                              hipStream_t stream) {
    (void)in_sizes; (void)n_in; (void)out_size; (void)ws_size;
    const float* fx   = (const float*)d_in[0];
    const float* sx   = (const float*)d_in[1];
    const float* adj  = (const float*)d_in[2];
    const float* Wf   = (const float*)d_in[3];
    const float* bfv  = (const float*)d_in[4];
    const float* Ws   = (const float*)d_in[5];
    const float* bsv  = (const float*)d_in[6];
    const float* Watt = (const float*)d_in[7];
    const float* batt = (const float*)d_in[8];
    float* out = (float*)d_out;

    char* ws = (char*)d_ws;
    float*  d_inv = (float*)(ws);                      // 32 KB
    bf16_t* Yt    = (bf16_t*)(ws + 32768);             // 8 MB   [512][8192]
    bf16_t* Wtf   = (bf16_t*)(ws + 8421376);           // 128 KB
    bf16_t* Wts   = (bf16_t*)(ws + 8552448);           // 128 KB
    bf16_t* msgp  = (bf16_t*)(ws + 8683520);           // 4 x 8 MB bf16 partials

    const int SK = 4;                                  // KCH = 2048
    k_rowsum<<<NROWS / 4 + 256, 256, 0, stream>>>(adj, d_inv, Wf, Ws, Wtf, Wts);
    k_prep_x<<<dim3(NROWS / 64, NCAT / 64), 256, 0, stream>>>(fx, sx, d_inv, Yt);
    k_gemm7<<<256 * SK, 256, 0, stream>>>(adj, Yt, msgp, NROWS / SK);
    k_fuse<4><<<NROWS / 32, 256, 0, stream>>>(msgp, d_inv, Wtf, Wts, bfv,
                                              bsv, Watt, batt, out);
}

// Round 8
// 160.546 us; speedup vs baseline: 1.1527x; 1.1527x over previous
//
#include <hip/hip_runtime.h>
#include <hip/hip_bf16.h>

// ---- types ----
typedef __bf16 bf16_t;
typedef __bf16 bf16x8 __attribute__((ext_vector_type(8)));
typedef __bf16 bf16x4 __attribute__((ext_vector_type(4)));
typedef float  f32x4  __attribute__((ext_vector_type(4)));

#define NROWS 8192
#define INDIM 256
#define HID   256
#define NCAT  512

// async global->LDS retained only for reference; A staging is reg-cvt.
__device__ __forceinline__ void gload16(const bf16_t* g, bf16_t* l) {
    __builtin_amdgcn_global_load_lds(
        (const __attribute__((address_space(1))) void*)g,
        (__attribute__((address_space(3))) void*)l,
        16, 0, 0);
}

// raw barrier (no implicit cnt drain)
__device__ __forceinline__ void bar() {
    asm volatile("" ::: "memory");
    __builtin_amdgcn_s_barrier();
    asm volatile("" ::: "memory");
}

#define LGKM0  asm volatile("s_waitcnt lgkmcnt(0)" ::: "memory")

// ============ kernel 1: row sums (read-only) + weight transposes ============
__global__ __launch_bounds__(256) void k_rowsum(const float* __restrict__ adj,
                                                float* __restrict__ d_inv,
                                                const float* __restrict__ Wf,
                                                const float* __restrict__ Ws,
                                                bf16_t* __restrict__ Wtf,
                                                bf16_t* __restrict__ Wts) {
    const int b = blockIdx.x;
    if (b >= NROWS / 4) {
        const int i = (b - NROWS / 4) * 256 + threadIdx.x;
        const int n = i >> 8, k = i & 255;
        Wtf[i] = (bf16_t)Wf[k * 256 + n];
        Wts[i] = (bf16_t)Ws[k * 256 + n];
        return;
    }
    const int lane = threadIdx.x & 63;
    const int wid  = threadIdx.x >> 6;
    const int row  = b * 4 + wid;
    const float4* rp = (const float4*)(adj + (size_t)row * NROWS);
    float s = 0.f;
#pragma unroll 8
    for (int i = lane; i < NROWS / 4; i += 64) {
        float4 v = rp[i];
        s += (v.x + v.y) + (v.z + v.w);
    }
#pragma unroll
    for (int off = 32; off; off >>= 1) s += __shfl_down(s, off);
    if (lane == 0) d_inv[row] = 1.0f / sqrtf(s + 1e-9f);
}

// ====== kernel 2: Ytf = fragment-ordered bf16(d_j * X[j][c]) ================
// Layout: Ytf[G][kt][ks*2+ni][lane][8e]  (bf16), G = c>>5 (16 groups of 32
// features), kt = j>>6 (128 K-tiles), lane = (c&15) + ((j&31)>>3)*16,
// e = j&7, ks = (j&63)>>5, ni = (c&31)>>4.  The GEMM's B-fragment load for
// (G,kt,ks,ni) is then exactly base + lane*16B: one coalesced dwordx4/lane,
// L2-resident, no LDS staging needed.
__global__ __launch_bounds__(256) void k_prep_x(const float* __restrict__ fx,
                                                const float* __restrict__ sx,
                                                const float* __restrict__ d_inv,
                                                bf16_t* __restrict__ Ytf) {
    __shared__ bf16_t T[64][72];
    const int tid = threadIdx.x;
    const int j0 = blockIdx.x * 64;              // node block = one kt
    const int c0 = blockIdx.y * 64;              // feature block = 2 G groups
    const float* src = (c0 < 256) ? fx : sx;
    const int cc0 = (c0 < 256) ? c0 : (c0 - 256);
#pragma unroll
    for (int i = 0; i < 4; ++i) {
        int s = tid + i * 256;
        int jr = s >> 4, c4 = (s & 15) * 4;
        float dj = d_inv[j0 + jr];
        float4 v = *(const float4*)(src + (size_t)(j0 + jr) * 256 + cc0 + c4);
        bf16x4 o;
        o[0] = (bf16_t)(v.x * dj); o[1] = (bf16_t)(v.y * dj);
        o[2] = (bf16_t)(v.z * dj); o[3] = (bf16_t)(v.w * dj);
        *(bf16x4*)(&T[jr][c4]) = o;
    }
    __syncthreads();
    // write: wave w -> (ni = w&1, ks = w>>1); iter i -> Gs; lane l ->
    // (c_low = l&15, j8 = l>>4).  Each wave-iter stores contiguous 1KB.
    const int lane = tid & 63, w = tid >> 6;
    const int ni = w & 1, ks = w >> 1;
#pragma unroll
    for (int Gs = 0; Gs < 2; ++Gs) {
        const int cr = Gs * 32 + ni * 16 + (lane & 15);
        const int jb = (ks * 4 + (lane >> 4)) * 8;
        bf16x8 o;
#pragma unroll
        for (int e = 0; e < 8; ++e) o[e] = T[jb + e][cr];
        size_t off = ((size_t)(blockIdx.y * 2 + Gs) * 128 + blockIdx.x) * 2048
                   + (size_t)(ks * 2 + ni) * 512 + (size_t)lane * 8;
        *(bf16x8*)(Ytf + off) = o;
    }
}

// ========= kernel 3: 256x256 GEMM, 4-phase, A-in-LDS + B-direct-from-L2 =====
// R6 skeleton (verified) with B's LDS round-trip removed: B fragments load
// straight from fragment-ordered Ytf (coalesced dwordx4, L2-resident 2MB per
// XCD-pair), prefetched one phase ahead in R6's preread slots.  No B DMA, no
// B ds_reads, no B barriers, no manual VMCNTs anywhere (all waits are
// compiler-counted: a_write's wait on R, MFMA's wait on bA/bB).
// A path unchanged: reg-cvt fp32->bf16, write-side XOR swizzle, 2-tile-ahead
// into 4 half-slots; cross-wave distances as R6 (write lgkm-certified >=3
// barriers before cross-wave read; prereads certified >=1 barrier before
// slot overwrite).

__device__ __forceinline__ void a_load_half(const float* Ag, int h, size_t k2,
                                            int tid, f32x4 R[4]) {
#pragma unroll
    for (int c = 0; c < 2; ++c) {
        const float* p = Ag + (size_t)(h * 128 + c * 64 + (tid >> 3)) * NROWS
                            + k2 + (tid & 7) * 8;
        R[c * 2 + 0] = *(const f32x4*)(p);
        R[c * 2 + 1] = *(const f32x4*)(p + 4);
    }
}

__device__ __forceinline__ void a_write_half(bf16_t* dst, const f32x4 R[4],
                                             int tid) {
#pragma unroll
    for (int c = 0; c < 2; ++c) {
        int r   = c * 64 + (tid >> 3);
        int col = ((tid & 7) * 8) ^ ((r & 7) * 8);
        f32x4 v0 = R[c * 2], v1 = R[c * 2 + 1];
        bf16x8 o;
        o[0] = (bf16_t)v0[0]; o[1] = (bf16_t)v0[1];
        o[2] = (bf16_t)v0[2]; o[3] = (bf16_t)v0[3];
        o[4] = (bf16_t)v1[0]; o[5] = (bf16_t)v1[1];
        o[6] = (bf16_t)v1[2]; o[7] = (bf16_t)v1[3];
        *(bf16x8*)(dst + r * 64 + col) = o;
    }
}

__device__ __forceinline__ void frag_a(const bf16_t* base, bf16x8 af[4][2],
                                       int arow, int c0, int c1) {
#pragma unroll
    for (int mi = 0; mi < 4; ++mi) {
        af[mi][0] = *(const bf16x8*)(base + (arow + mi * 16) * 64 + c0);
        af[mi][1] = *(const bf16x8*)(base + (arow + mi * 16) * 64 + c1);
    }
}

// B fragment set (2 ni x 2 ks) direct from fragment-ordered Ytf
__device__ __forceinline__ void frag_bg(const bf16_t* p, bf16x8 bf2[2][2]) {
#pragma unroll
    for (int ks = 0; ks < 2; ++ks)
#pragma unroll
        for (int ni = 0; ni < 2; ++ni)
            bf2[ni][ks] = *(const bf16x8*)(p + (ks * 2 + ni) * 512);
}

template <int Q>
__device__ __forceinline__ void mfma_q(f32x4 acc[4][4][2],
                                       const bf16x8 af[4][2],
                                       const bf16x8 bf2[2][2]) {
    __builtin_amdgcn_s_setprio(1);
#pragma unroll
    for (int ks = 0; ks < 2; ++ks)
#pragma unroll
        for (int mi = 0; mi < 4; ++mi)
#pragma unroll
            for (int ni = 0; ni < 2; ++ni)
                acc[Q][mi][ni] = __builtin_amdgcn_mfma_f32_16x16x32_bf16(
                    af[mi][ks], bf2[ni][ks], acc[Q][mi][ni], 0, 0, 0);
    __builtin_amdgcn_s_setprio(0);
}

__global__ __launch_bounds__(512, 2) void k_gemm8(const float* __restrict__ adj,
                                                  const bf16_t* __restrict__ Ytf,
                                                  bf16_t* __restrict__ msgp,
                                                  int KCH) {
    __shared__ bf16_t SH[8 * 8192];              // 128 KB (A slots + epilogue)
    bf16_t* As = SH;                             // A half-slots 0..3 (64 KB)
    const int tid  = threadIdx.x;
    const int lane = tid & 63;
    const int w    = tid >> 6;
    const int wrow = w >> 2, wcol = w & 3;       // 2M x 4N waves
    const int lr = lane & 15, hi = lane >> 4;

    // z-per-XCD decode (round-robin dispatch assumption; perf heuristic only)
    const int bid = blockIdx.x;
    const int c  = bid & 7;                      // XCD
    const int j  = bid >> 3;                     // 0..31 within XCD
    const int z  = c >> 1;                       // K-chunk pinned to XCD pair
    const int y  = (c & 1) * 16 + (j >> 1);
    const int x  = j & 1;
    const int m0 = y * 256, n0 = x * 256;
    const size_t kbase = (size_t)z * KCH;

    const float* Ag = adj + (size_t)m0 * NROWS + kbase;
    // B fragment base pointers: group GA = n0/32 + wcol (bA), +4 (bB);
    // kt_global = z*32 + t.
    const bf16_t* pBA = Ytf
        + ((size_t)((n0 >> 5) + wcol) * 128 + (size_t)z * 32) * 2048
        + (size_t)lane * 8;
    const bf16_t* pBB = pBA + (size_t)4 * 128 * 2048;

    const int sw = (lr & 7) * 8;                 // A read-side swizzle
    const int c0 = (hi * 8) ^ sw;
    const int c1 = c0 ^ 32;
    const int arow = wrow * 64 + lr;

    f32x4 acc[4][4][2] = {};
    const int NT = KCH / 64;                     // tiles (even)

    // steady-state register state
    f32x4 R[4];                                  // A staging buffer (16 VGPR)
    bf16x8 af[4][2], bA[2][2], bB[2][2];         // MFMA fragments (64 VGPR)

    // prologue: A tiles 0,1 via reg-cvt (no B staging needed)
    {
        f32x4 T[4];
        a_load_half(Ag, 0, 0, tid, R);
        a_load_half(Ag, 1, 0, tid, T);
        a_write_half(As + 0 * 8192, R, tid);
        a_write_half(As + 1 * 8192, T, tid);
        a_load_half(Ag, 0, 64, tid, R);
        a_load_half(Ag, 1, 64, tid, T);
        a_write_half(As + 2 * 8192, R, tid);
        a_write_half(As + 3 * 8192, T, tid);
        a_load_half(Ag, 0, 128, tid, R);         // R <- (t2,h0), in flight
        LGKM0;                                   // own ds_writes published
    }
    bar();                                       // ALL waves' writes visible
    // preload tile-0 Ph1 fragments (af cross-wave-safe after bar; bA private)
    frag_a(As + 0 * 8192, af, arow, c0, c1);
    frag_bg(pBA, bA);                            // bA(t=0)

    // per-tile body: 4 phases (Q00,Q01,Q11,Q10), MFMA first, then staging +
    // prereads.  B fragments: bB(t) loaded Ph1, bA(t+1) loaded Ph4.
#define TBODY(PP, tt)                                                         \
    {                                                                         \
        bf16_t* Ah0 = As + ((PP) * 2 + 0) * 8192;                             \
        bf16_t* Ah1 = As + ((PP) * 2 + 1) * 8192;                             \
        bf16_t* An0 = As + (((PP) ^ 1) * 2 + 0) * 8192;                       \
        const bool full  = ((tt) <= NT - 3);                                  \
        const bool fnext = ((tt) <= NT - 4);                                  \
        const size_t k2 = (size_t)((tt) + 2) * 64;                            \
        const size_t k3 = (size_t)((tt) + 3) * 64;                            \
        /* Ph1: MFMA Q00; load bB(t) [global, certified pre-Q01]. */          \
        mfma_q<0>(acc, af, bA);                                               \
        frag_bg(pBB + (size_t)(tt) * 2048, bB);                               \
        bar();                                                                \
        /* Ph2: MFMA Q01; A staging (Ah0<-R, R<-(t+2,h1)); preread af<-Ah1.*/ \
        mfma_q<1>(acc, af, bB);                                               \
        if (full) {                                                           \
            a_write_half(Ah0, R, tid);                                        \
            a_load_half(Ag, 1, k2, tid, R);                                   \
        }                                                                     \
        frag_a(Ah1, af, arow, c0, c1);                                        \
        bar();                                                                \
        /* Ph3: MFMA Q11. */                                                  \
        mfma_q<3>(acc, af, bB);                                               \
        bar();                                                                \
        /* Ph4: MFMA Q10; Ah1<-R; R<-(t+3,h0); prereads af<-An0, bA(t+1). */  \
        mfma_q<2>(acc, af, bA);                                               \
        if (full) a_write_half(Ah1, R, tid);                                  \
        if (fnext) a_load_half(Ag, 0, k3, tid, R);                            \
        if ((tt) != NT - 1) {                                                 \
            frag_a(An0, af, arow, c0, c1);                                    \
            frag_bg(pBA + (size_t)((tt) + 1) * 2048, bA);                     \
        }                                                                     \
        bar();                                                                \
    }

    for (int t = 0; t < NT; t += 2) {
        TBODY(0, t);
        TBODY(1, t + 1);
    }
#undef TBODY

    // epilogue: LDS-transpose each 128x128 quadrant, store bf16 coalesced
    bf16_t* mpb = msgp + (size_t)z * NROWS * NCAT;
    float* ep = (float*)SH;                      // 128 x (stride 133) fp32
    const int erow = tid >> 2, ecb = (tid & 3) * 32;
#pragma unroll
    for (int q4 = 0; q4 < 4; ++q4) {
        const int qm = q4 >> 1, qn = q4 & 1;
        bar();
#pragma unroll
        for (int mi = 0; mi < 4; ++mi)
#pragma unroll
            for (int ni = 0; ni < 2; ++ni)
#pragma unroll
                for (int r = 0; r < 4; ++r)
                    ep[(wrow * 64 + mi * 16 + hi * 4 + r) * 133
                       + wcol * 32 + ni * 16 + lr] = acc[q4][mi][ni][r];
        LGKM0;
        bar();
        bf16_t* gp = mpb + (size_t)(m0 + qm * 128 + erow) * NCAT
                         + n0 + qn * 128 + ecb;
#pragma unroll
        for (int j2 = 0; j2 < 4; ++j2) {
            f32x4 v0 = *(const f32x4*)(ep + erow * 133 + ecb + j2 * 8);
            f32x4 v1 = *(const f32x4*)(ep + erow * 133 + ecb + j2 * 8 + 4);
            bf16x8 o;
            o[0] = (bf16_t)v0[0]; o[1] = (bf16_t)v0[1];
            o[2] = (bf16_t)v0[2]; o[3] = (bf16_t)v0[3];
            o[4] = (bf16_t)v1[0]; o[5] = (bf16_t)v1[1];
            o[6] = (bf16_t)v1[2]; o[7] = (bf16_t)v1[3];
            *(bf16x8*)(gp + j2 * 8) = o;
        }
    }
}

// ===================== kernel 4: H_f/H_s + attention + blend =================
template <int NP>
__global__ __launch_bounds__(256) void k_fuse(const bf16_t* __restrict__ msg,
                                              const float* __restrict__ d_inv,
                                              const bf16_t* __restrict__ Wtf,
                                              const bf16_t* __restrict__ Wts,
                                              const float* __restrict__ bfv,
                                              const float* __restrict__ bsv,
                                              const float* __restrict__ Watt,
                                              const float* __restrict__ batt,
                                              float* __restrict__ out) {
    __shared__ bf16_t Ms[32][520];
    __shared__ float attnbuf[4][32];
    const int tid = threadIdx.x, lane = tid & 63, w = tid >> 6;
    const int r0 = blockIdx.x * 32;
    const int lr = lane & 15, lk = (lane >> 4) * 8;

#pragma unroll
    for (int i = 0; i < 8; ++i) {
        int s = tid + i * 256;              // 0..2047
        int r = s >> 6, c8 = (s & 63) * 8;
        float di = d_inv[r0 + r];
        size_t off = (size_t)(r0 + r) * NCAT + c8;
        float a8[8] = {};
#pragma unroll
        for (int p = 0; p < NP; ++p) {
            bf16x8 v = *(const bf16x8*)(msg + (size_t)p * NROWS * NCAT + off);
#pragma unroll
            for (int j = 0; j < 8; ++j) a8[j] += (float)v[j];
        }
        bf16x8 o;
#pragma unroll
        for (int j = 0; j < 8; ++j) o[j] = (bf16_t)(a8[j] * di);
        *(bf16x8*)(&Ms[r][c8]) = o;
    }
    __syncthreads();

    f32x4 accf[2][4] = {}, accs[2][4] = {};
#pragma unroll
    for (int ks = 0; ks < 8; ++ks) {
        bf16x8 af[2], as2[2];
#pragma unroll
        for (int mi = 0; mi < 2; ++mi) {
            af[mi]  = *(const bf16x8*)(&Ms[mi * 16 + lr][ks * 32 + lk]);
            as2[mi] = *(const bf16x8*)(&Ms[mi * 16 + lr][256 + ks * 32 + lk]);
        }
#pragma unroll
        for (int ni = 0; ni < 4; ++ni) {
            int col = w * 64 + ni * 16 + lr;
            bf16x8 bwf = *(const bf16x8*)(Wtf + col * 256 + ks * 32 + lk);
            bf16x8 bws = *(const bf16x8*)(Wts + col * 256 + ks * 32 + lk);
#pragma unroll
            for (int mi = 0; mi < 2; ++mi) {
                accf[mi][ni] = __builtin_amdgcn_mfma_f32_16x16x32_bf16(
                    af[mi], bwf, accf[mi][ni], 0, 0, 0);
                accs[mi][ni] = __builtin_amdgcn_mfma_f32_16x16x32_bf16(
                    as2[mi], bws, accs[mi][ni], 0, 0, 0);
            }
        }
    }

    float par[2][4] = {};
#pragma unroll
    for (int ni = 0; ni < 4; ++ni) {
        int col = w * 64 + ni * 16 + lr;
        float bf_ = bfv[col], bs_ = bsv[col];
        float wf = Watt[col], ws_ = Watt[256 + col];
#pragma unroll
        for (int mi = 0; mi < 2; ++mi)
#pragma unroll
            for (int r = 0; r < 4; ++r) {
                float f = accf[mi][ni][r] + bf_; f = f > 0.f ? f : 0.f;
                float s = accs[mi][ni][r] + bs_; s = s > 0.f ? s : 0.f;
                accf[mi][ni][r] = f; accs[mi][ni][r] = s;
                par[mi][r] += f * wf + s * ws_;
            }
    }
#pragma unroll
    for (int off = 1; off < 16; off <<= 1)
#pragma unroll
        for (int mi = 0; mi < 2; ++mi)
#pragma unroll
            for (int r = 0; r < 4; ++r)
                par[mi][r] += __shfl_xor(par[mi][r], off);
    if (lr == 0) {
#pragma unroll
        for (int mi = 0; mi < 2; ++mi)
#pragma unroll
            for (int r = 0; r < 4; ++r)
                attnbuf[w][mi * 16 + (lane >> 4) * 4 + r] = par[mi][r];
    }
    __syncthreads();

    const float ba = batt[0];
#pragma unroll
    for (int mi = 0; mi < 2; ++mi)
#pragma unroll
        for (int r = 0; r < 4; ++r) {
            int rr = mi * 16 + (lane >> 4) * 4 + r;
            float tot = attnbuf[0][rr] + attnbuf[1][rr] + attnbuf[2][rr] +
                        attnbuf[3][rr] + ba;
            float attn = 1.0f / (1.0f + expf(-tot));
#pragma unroll
            for (int ni = 0; ni < 4; ++ni) {
                int col = w * 64 + ni * 16 + lr;
                out[(size_t)(r0 + rr) * 256 + col] =
                    attn * accf[mi][ni][r] + (1.0f - attn) * accs[mi][ni][r];
            }
        }
}

// ===================== launch =====================
extern "C" void kernel_launch(void* const* d_in, const int* in_sizes, int n_in,
                              void* d_out, int out_size, void* d_ws, size_t ws_size,
                              hipStream_t stream) {
    (void)in_sizes; (void)n_in; (void)out_size; (void)ws_size;
    const float* fx   = (const float*)d_in[0];
    const float* sx   = (const float*)d_in[1];
    const float* adj  = (const float*)d_in[2];
    const float* Wf   = (const float*)d_in[3];
    const float* bfv  = (const float*)d_in[4];
    const float* Ws   = (const float*)d_in[5];
    const float* bsv  = (const float*)d_in[6];
    const float* Watt = (const float*)d_in[7];
    const float* batt = (const float*)d_in[8];
    float* out = (float*)d_out;

    char* ws = (char*)d_ws;
    float*  d_inv = (float*)(ws);                      // 32 KB
    bf16_t* Ytf   = (bf16_t*)(ws + 32768);             // 8 MB fragment-ordered
    bf16_t* Wtf   = (bf16_t*)(ws + 8421376);           // 128 KB
    bf16_t* Wts   = (bf16_t*)(ws + 8552448);           // 128 KB
    bf16_t* msgp  = (bf16_t*)(ws + 8683520);           // 4 x 8 MB bf16 partials

    const int SK = 4;                                  // KCH = 2048
    k_rowsum<<<NROWS / 4 + 256, 256, 0, stream>>>(adj, d_inv, Wf, Ws, Wtf, Wts);
    k_prep_x<<<dim3(NROWS / 64, NCAT / 64), 256, 0, stream>>>(fx, sx, d_inv, Ytf);
    k_gemm8<<<64 * SK, 512, 0, stream>>>(adj, Ytf, msgp, NROWS / SK);
    k_fuse<4><<<NROWS / 32, 256, 0, stream>>>(msgp, d_inv, Wtf, Wts, bfv,
                                              bsv, Watt, batt, out);
}